// Round 1
// baseline (341.194 us; speedup 1.0000x reference)
//
#include <hip/hip_runtime.h>
#include <hip/hip_bf16.h>

// B=16, C=512, N=4096 (64x64), CP=64.
// out = gamma*(wo@softmax((wk x)(wq x)^T)@(wv x)+bo)+x
// 4-kernel bf16-MFMA pipeline, minimal global traffic:
//   k_qkv:    x read once (HBM floor), w in LDS, x gathered per-lane -> q,k [cp][n], vt [n][cp]
//   k_energy: 8 K-splits, LDS-atomic block reduction -> epart 2 MB fp32
//   k_softmax: rowwise softmax -> attn bf16
//   k_avout:  attn*V (avt in LDS only) + wo-proj + bias + gamma + residual, float4 epilogue

#define NN 4096
#define CIN 512
#define CPD 64

typedef short s8v __attribute__((ext_vector_type(8)));
typedef float f4v __attribute__((ext_vector_type(4)));

__device__ __forceinline__ unsigned short f2bf(float f) {
    union { float f; unsigned int u; } c; c.f = f;
    unsigned int r = c.u + 0x7FFFu + ((c.u >> 16) & 1u);   // RNE
    return (unsigned short)(r >> 16);
}

// ---------------- K1: QKV. A = w (LDS bf16, swizzled), B = x (direct global gather).
// grid (16 nb, 16 b), block 512 (8 waves, each 32 n-cols). D[row=o][col=n].
__global__ __launch_bounds__(512, 2) void k_qkv(
    const float* __restrict__ x,
    const float* __restrict__ wq, const float* __restrict__ bq,
    const float* __restrict__ wk, const float* __restrict__ bk,
    const float* __restrict__ wv, const float* __restrict__ bv,
    unsigned short* __restrict__ q, unsigned short* __restrict__ k,
    unsigned short* __restrict__ vt)
{
    const int nb = blockIdx.x, b = blockIdx.y;
    const int t = threadIdx.x;
    const int wv_ = t >> 6, L = t & 63, quad = L >> 4, l15 = L & 15;
    const int swz = (l15 & 7) * 8;

    __shared__ unsigned short wl[3][64 * 128];   // [p][o][c-chunk 128], 48 KB

    const float* wptr[3] = { wq, wk, wv };

    f4v acc[3][4][2];   // [p][ot][ntc]
    #pragma unroll
    for (int p = 0; p < 3; ++p)
        #pragma unroll
        for (int ot = 0; ot < 4; ++ot)
            #pragma unroll
            for (int nn = 0; nn < 2; ++nn) acc[p][ot][nn] = (f4v){0.f,0.f,0.f,0.f};

    const int n_col0 = nb * 256 + wv_ * 32 + l15;   // lane's column for ntc=0
    const size_t xbase = (size_t)b * CIN * NN;

    for (int cc = 0; cc < 4; ++cc) {            // c-chunks of 128
        __syncthreads();
        // stage w chunk (all 3 projections), fp32->bf16, XOR-swizzled
        {
            const int o   = t & 63;
            const int c16 = (t >> 6) * 16;
            const int osw = (o & 7) * 8;
            #pragma unroll
            for (int p = 0; p < 3; ++p) {
                const float* wp = wptr[p] + (size_t)o * CIN + cc * 128 + c16;
                unsigned short tmp[16];
                #pragma unroll
                for (int f = 0; f < 4; ++f) {
                    float4 v = *(const float4*)(wp + f * 4);
                    tmp[f*4+0] = f2bf(v.x); tmp[f*4+1] = f2bf(v.y);
                    tmp[f*4+2] = f2bf(v.z); tmp[f*4+3] = f2bf(v.w);
                }
                #pragma unroll
                for (int u = 0; u < 2; ++u)
                    *(uint4*)&wl[p][o * 128 + ((c16 + u * 8) ^ osw)] =
                        *(const uint4*)&tmp[u * 8];
            }
        }
        __syncthreads();

        #pragma unroll
        for (int ksl = 0; ksl < 4; ++ksl) {
            const int c = cc * 128 + ksl * 32 + quad * 8;
            // gather B-fragments from global x (lanes = consecutive n -> 64B segs)
            float bx0[8], bx1[8];
            #pragma unroll
            for (int j = 0; j < 8; ++j) {
                const float* xc = x + xbase + (size_t)(c + j) * NN + n_col0;
                bx0[j] = xc[0];
                bx1[j] = xc[16];
            }
            s8v bf0, bf1;
            #pragma unroll
            for (int j = 0; j < 8; ++j) {
                bf0[j] = (short)f2bf(bx0[j]);
                bf1[j] = (short)f2bf(bx1[j]);
            }
            const int cfrag = (ksl * 32 + quad * 8) ^ swz;
            #pragma unroll
            for (int p = 0; p < 3; ++p)
                #pragma unroll
                for (int ot = 0; ot < 4; ++ot) {
                    s8v af = *(const s8v*)&wl[p][(ot * 16 + l15) * 128 + cfrag];
                    acc[p][ot][0] = __builtin_amdgcn_mfma_f32_16x16x32_bf16(
                        af, bf0, acc[p][ot][0], 0, 0, 0);
                    acc[p][ot][1] = __builtin_amdgcn_mfma_f32_16x16x32_bf16(
                        af, bf1, acc[p][ot][1], 0, 0, 0);
                }
        }
    }

    // epilogue: D rows o = ot*16+quad*4+r, cols n = n_col0 + ntc*16
    const float* biasp[3] = { bq, bk, bv };
    #pragma unroll
    for (int p = 0; p < 2; ++p) {
        unsigned short* outp = ((p == 0) ? q : k) + (size_t)b * CPD * NN;
        #pragma unroll
        for (int ot = 0; ot < 4; ++ot) {
            float4 b4 = *(const float4*)(biasp[p] + ot * 16 + quad * 4);
            const float bsv[4] = { b4.x, b4.y, b4.z, b4.w };
            #pragma unroll
            for (int nn = 0; nn < 2; ++nn) {
                const int n = n_col0 + nn * 16;
                #pragma unroll
                for (int r = 0; r < 4; ++r) {
                    int o = ot * 16 + quad * 4 + r;
                    outp[(size_t)o * NN + n] = f2bf(acc[p][ot][nn][r] + bsv[r]);
                }
            }
        }
    }
    {
        unsigned short* vtb = vt + (size_t)b * NN * CPD;
        #pragma unroll
        for (int ot = 0; ot < 4; ++ot) {
            float4 b4 = *(const float4*)(bv + ot * 16 + quad * 4);
            const float bsv[4] = { b4.x, b4.y, b4.z, b4.w };
            #pragma unroll
            for (int nn = 0; nn < 2; ++nn) {
                const int n = n_col0 + nn * 16;
                unsigned short tmp[4];
                #pragma unroll
                for (int r = 0; r < 4; ++r) tmp[r] = f2bf(acc[2][ot][nn][r] + bsv[r]);
                *(uint2*)(vtb + (size_t)n * CPD + ot * 16 + quad * 4) = *(const uint2*)tmp;
            }
        }
    }
}

// ---------------- K2: energy partials, 8 K-splits, LDS-atomic block reduction.
__global__ __launch_bounds__(256) void k_energy(
    const unsigned short* __restrict__ q, const unsigned short* __restrict__ k,
    float* __restrict__ epart)   // [b][8][64][64] fp32
{
    const int s = blockIdx.x;   // 8 K-chunks of 512 n
    const int b = blockIdx.y;
    const int t = threadIdx.x;
    const int wv_ = t >> 6, L = t & 63, quad = L >> 4, l15 = L & 15;
    const unsigned short* kb = k + (size_t)b * CPD * NN;
    const unsigned short* qb = q + (size_t)b * CPD * NN;

    __shared__ float red[64 * 65];

    f4v acc[4][4];
    #pragma unroll
    for (int a = 0; a < 4; ++a)
        #pragma unroll
        for (int d = 0; d < 4; ++d) acc[a][d] = (f4v){0.f,0.f,0.f,0.f};

    const int nbase = s * 512 + wv_ * 128;
    #pragma unroll
    for (int ks = 0; ks < 4; ++ks) {
        const int n = nbase + ks * 32 + quad * 8;
        s8v af[4], bf_[4];
        #pragma unroll
        for (int it = 0; it < 4; ++it)
            af[it] = *(const s8v*)(kb + (size_t)(it * 16 + l15) * NN + n);
        #pragma unroll
        for (int jt = 0; jt < 4; ++jt)
            bf_[jt] = *(const s8v*)(qb + (size_t)(jt * 16 + l15) * NN + n);
        #pragma unroll
        for (int it = 0; it < 4; ++it)
            #pragma unroll
            for (int jt = 0; jt < 4; ++jt)
                acc[it][jt] = __builtin_amdgcn_mfma_f32_16x16x32_bf16(
                    af[it], bf_[jt], acc[it][jt], 0, 0, 0);
    }

    for (int idx = t; idx < 64 * 65; idx += 256) red[idx] = 0.f;
    __syncthreads();
    #pragma unroll
    for (int it = 0; it < 4; ++it)
        #pragma unroll
        for (int jt = 0; jt < 4; ++jt)
            #pragma unroll
            for (int r = 0; r < 4; ++r)
                atomicAdd(&red[(it * 16 + quad * 4 + r) * 65 + jt * 16 + l15],
                          acc[it][jt][r]);
    __syncthreads();
    float* ep = epart + ((size_t)b * 8 + s) * 4096;
    for (int idx = t; idx < 4096; idx += 256)
        ep[idx] = red[(idx >> 6) * 65 + (idx & 63)];
}

// ---------------- K3: sum 8 partials + softmax over j -> attn bf16 [b][i][j]
__global__ __launch_bounds__(64) void k_softmax(
    const float* __restrict__ epart, unsigned short* __restrict__ attn)
{
    const int i = blockIdx.x;
    const int b = blockIdx.y;
    const int j = threadIdx.x;
    float s = 0.f;
    #pragma unroll
    for (int sp = 0; sp < 8; ++sp)
        s += epart[((size_t)b * 8 + sp) * 4096 + i * 64 + j];
    float m = s;
    #pragma unroll
    for (int off = 32; off; off >>= 1) m = fmaxf(m, __shfl_xor(m, off));
    float e = __expf(s - m);
    float tot = e;
    #pragma unroll
    for (int off = 32; off; off >>= 1) tot += __shfl_xor(tot, off);
    attn[(size_t)b * 4096 + i * 64 + j] = f2bf(e / tot);
}

// ---------------- K4: fused attn*V + out-proj + residual.
// grid (32 nb, 16 b), block 256 (4 waves, each 32 n). n-tile 128.
// phase1: D1[i-row][n-col] = attn x vt -> avl LDS [n][i] (swizzled)
// phase2: D2[n-row][c-col] = avl x wo -> float4 epilogue along n
__global__ __launch_bounds__(256) void k_avout(
    const unsigned short* __restrict__ vt, const unsigned short* __restrict__ attn,
    const float* __restrict__ wo, const float* __restrict__ bo,
    const float* __restrict__ gamma, const float* __restrict__ x,
    float* __restrict__ out)
{
    const int nb = blockIdx.x, b = blockIdx.y;
    const int t = threadIdx.x;
    const int wv_ = t >> 6, L = t & 63, quad = L >> 4, l15 = L & 15;
    const int swz = (l15 & 7) * 8;

    __shared__ unsigned short wol[512 * 64];   // [c][i], swizzled, 64 KB
    __shared__ unsigned short avl[128 * 64];   // [n][i], swizzled, 16 KB

    // stage full wo (fp32 -> bf16)
    {
        const int i16 = (t & 3) * 16;
        #pragma unroll
        for (int pass = 0; pass < 8; ++pass) {
            const int c = (t >> 2) + pass * 64;
            const int csw = (c & 7) * 8;
            const float* wp = wo + (size_t)c * CPD + i16;
            unsigned short tmp[16];
            #pragma unroll
            for (int f = 0; f < 4; ++f) {
                float4 v = *(const float4*)(wp + f * 4);
                tmp[f*4+0] = f2bf(v.x); tmp[f*4+1] = f2bf(v.y);
                tmp[f*4+2] = f2bf(v.z); tmp[f*4+3] = f2bf(v.w);
            }
            #pragma unroll
            for (int u = 0; u < 2; ++u)
                *(uint4*)&wol[c * 64 + ((i16 + u * 8) ^ csw)] = *(const uint4*)&tmp[u*8];
        }
    }

    // phase 1: avt tile (128 n-cols), A = attn (global), B = vt (global)
    {
        const unsigned short* ab  = attn + (size_t)b * 4096;
        const unsigned short* vtb = vt + (size_t)b * NN * CPD;
        const int n0 = nb * 128;
        f4v acc1[4][2];   // [it][ntc]
        #pragma unroll
        for (int a = 0; a < 4; ++a)
            #pragma unroll
            for (int d = 0; d < 2; ++d) acc1[a][d] = (f4v){0.f,0.f,0.f,0.f};
        #pragma unroll
        for (int ks = 0; ks < 2; ++ks) {
            const int j = ks * 32 + quad * 8;
            s8v af[4], bf_[2];
            #pragma unroll
            for (int it = 0; it < 4; ++it)
                af[it] = *(const s8v*)(ab + (size_t)(it * 16 + l15) * 64 + j);
            #pragma unroll
            for (int nn = 0; nn < 2; ++nn)
                bf_[nn] = *(const s8v*)(vtb +
                    (size_t)(n0 + wv_ * 32 + nn * 16 + l15) * CPD + j);
            #pragma unroll
            for (int it = 0; it < 4; ++it)
                #pragma unroll
                for (int nn = 0; nn < 2; ++nn)
                    acc1[it][nn] = __builtin_amdgcn_mfma_f32_16x16x32_bf16(
                        af[it], bf_[nn], acc1[it][nn], 0, 0, 0);
        }
        // write avl[n][i]: i = it*16+quad*4+r, n_local = wv_*32+ntc*16+l15
        #pragma unroll
        for (int it = 0; it < 4; ++it)
            #pragma unroll
            for (int nn = 0; nn < 2; ++nn) {
                const int nloc = wv_ * 32 + nn * 16 + l15;
                unsigned short tmp[4];
                #pragma unroll
                for (int r = 0; r < 4; ++r) tmp[r] = f2bf(acc1[it][nn][r]);
                *(uint2*)&avl[nloc * 64 + ((it * 16 + quad * 4) ^ swz)] =
                    *(const uint2*)tmp;
            }
    }
    __syncthreads();

    // phase 2: out = gamma*(wo@av + bo) + x, float4 along n
    const float g = gamma[0];
    const int n0 = nb * 128;
    for (int cb = 0; cb < 8; ++cb) {
        f4v acc2[2][4];   // [nt][ct]
        #pragma unroll
        for (int a = 0; a < 2; ++a)
            #pragma unroll
            for (int d = 0; d < 4; ++d) acc2[a][d] = (f4v){0.f,0.f,0.f,0.f};
        #pragma unroll
        for (int ks = 0; ks < 2; ++ks) {
            const int ic = (ks * 32 + quad * 8) ^ swz;
            s8v af2[2], bf2[4];
            #pragma unroll
            for (int nt = 0; nt < 2; ++nt)
                af2[nt] = *(const s8v*)&avl[(wv_ * 32 + nt * 16 + l15) * 64 + ic];
            #pragma unroll
            for (int ct = 0; ct < 4; ++ct)
                bf2[ct] = *(const s8v*)&wol[(cb * 64 + ct * 16 + l15) * 64 + ic];
            #pragma unroll
            for (int nt = 0; nt < 2; ++nt)
                #pragma unroll
                for (int ct = 0; ct < 4; ++ct)
                    acc2[nt][ct] = __builtin_amdgcn_mfma_f32_16x16x32_bf16(
                        af2[nt], bf2[ct], acc2[nt][ct], 0, 0, 0);
        }
        // D2 rows n = n0+wv_*32+nt*16+quad*4+r, cols c = cb*64+ct*16+l15
        #pragma unroll
        for (int nt = 0; nt < 2; ++nt)
            #pragma unroll
            for (int ct = 0; ct < 4; ++ct) {
                const int c = cb * 64 + ct * 16 + l15;
                const float bs = bo[c];
                const int nbase = n0 + wv_ * 32 + nt * 16 + quad * 4;
                const size_t idx = ((size_t)b * CIN + c) * NN + nbase;
                float4 xr = *(const float4*)(x + idx);
                float4 r4;
                r4.x = g * (acc2[nt][ct][0] + bs) + xr.x;
                r4.y = g * (acc2[nt][ct][1] + bs) + xr.y;
                r4.z = g * (acc2[nt][ct][2] + bs) + xr.z;
                r4.w = g * (acc2[nt][ct][3] + bs) + xr.w;
                *(float4*)(out + idx) = r4;
            }
    }
}

extern "C" void kernel_launch(void* const* d_in, const int* in_sizes, int n_in,
                              void* d_out, int out_size, void* d_ws, size_t ws_size,
                              hipStream_t stream) {
    const float* x  = (const float*)d_in[0];
    const float* wq = (const float*)d_in[1];
    const float* bq = (const float*)d_in[2];
    const float* wk = (const float*)d_in[3];
    const float* bk = (const float*)d_in[4];
    const float* wv = (const float*)d_in[5];
    const float* bv = (const float*)d_in[6];
    const float* wo = (const float*)d_in[7];
    const float* bo = (const float*)d_in[8];
    const float* gm = (const float*)d_in[9];
    float* out = (float*)d_out;

    // workspace (bytes), total ~27.4 MB:
    char* wsb = (char*)d_ws;
    unsigned short* q     = (unsigned short*)wsb;                 //  8.39 MB
    unsigned short* k     = (unsigned short*)(wsb + 8388608);     //  8.39 MB
    unsigned short* vt    = (unsigned short*)(wsb + 16777216);    //  8.39 MB
    float*          epart = (float*)(wsb + 25165824);             //  2.10 MB
    unsigned short* attn  = (unsigned short*)(wsb + 27262976);    //  0.13 MB

    k_qkv<<<dim3(16, 16), 512, 0, stream>>>(x, wq, bq, wk, bk, wv, bv, q, k, vt);
    k_energy<<<dim3(8, 16), 256, 0, stream>>>(q, k, epart);
    k_softmax<<<dim3(64, 16), 64, 0, stream>>>(epart, attn);
    k_avout<<<dim3(32, 16), 256, 0, stream>>>(vt, attn, wo, bo, gm, x, out);
}